// Round 6
// baseline (179.396 us; speedup 1.0000x reference)
//
#include <hip/hip_runtime.h>
#include <math.h>

#define BSZ 8
#define HH 480
#define WW 640
#define NPIX (HH*WW)          // 307200
#define VRES 100
#define NZB 80
#define NVOXB (VRES*VRES*NZB) // 800000
#define LM 480

// output layout (flat float32, return order)
#define OFF_COORDS 0LL
#define OFF_FEAT   9830400LL                     // 8*307200*4
#define OFF_MAPS   29491200LL                    // + 8*307200*8
#define OFF_POSES  36864000LL                    // + 8*4*480*480
#define OFF_REP    36864024LL                    // + 24

struct PtRes { float depth, X, Z; int g0, g1, g2, vox; bool valid; };

// C6: XLA-CPU fast-math style f32 chain — every division by a constant
// lowered to multiply-by-f32-reciprocal:
//   /100  -> *0.01f            /FOC -> *f32(1/FOC)          /0.05 -> *20.0f
// (1/0.05f rounds to exactly 20.0f; 1/100.0f to 0.00999999977648f)
__device__ __forceinline__ PtRes compute_pt(float draw, int u, int r, float rfoc) {
  PtRes p;
  p.depth = __fmul_rn(draw, 0.01f);
  p.X = __fadd_rn(__fmul_rn(__fmul_rn(__fsub_rn((float)u, 319.5f), p.depth), rfoc), 2.5f);
  p.Z = __fadd_rn(__fmul_rn(__fmul_rn(__fsub_rn((float)(HH - 1 - r), 239.5f), p.depth), rfoc), 0.88f);
  const float minZf = -0.4f;   // f32(-8*0.05) == f32(-0.4)
  const float maxZf = 3.6f;    // f32(72*0.05) == f32(3.6)
  p.valid = (p.X > 0.0f) & (p.X < 5.0f) & (p.depth > 0.0f) & (p.depth < 5.0f)
          & (p.Z > minZf) & (p.Z < maxZf);
  p.g0 = (int)floorf(__fmul_rn(p.X, 20.0f));
  p.g1 = (int)floorf(__fmul_rn(p.depth, 20.0f));
  p.g2 = (int)floorf(__fmul_rn(p.Z, 20.0f));
  int c0 = min(max(p.g0, 0), VRES - 1);
  int c1 = min(max(p.g1, 0), VRES - 1);
  int c2 = min(max(p.g2 + 8, 0), NZB - 1);
  p.vox = (c0 * VRES + c1) * NZB + c2;
  return p;
}

__global__ void pose_kernel(const float* __restrict__ pose_obs,
                            const float* __restrict__ poses_last,
                            float* __restrict__ out_poses,
                            float* __restrict__ params) {
  int b = threadIdx.x;
  if (b >= BSZ) return;
  float p0 = poses_last[b*3+0], p1 = poses_last[b*3+1], p2 = poses_last[b*3+2];
  float r0 = pose_obs[b*3+0],  r1 = pose_obs[b*3+1],  r2 = pose_obs[b*3+2];
  const float DEGf = (float)57.29577951308232;
  // /DEG -> * f32 reciprocal (fast-math), 1/57.29577951308232 = 0.017453292519943295
  float thf = __fmul_rn(p2, (float)0.017453292519943295);
  float sth = (float)sin((double)thf);
  float cth = (float)cos((double)thf);
  float y = __fadd_rn(__fadd_rn(p1, __fmul_rn(r0, sth)), __fmul_rn(r1, cth));
  float x = __fsub_rn(__fadd_rn(p0, __fmul_rn(r0, cth)), __fmul_rn(r1, sth));
  float t = __fadd_rn(p2, __fmul_rn(r2, DEGf));
  t = __fadd_rn(fmodf(__fsub_rn(t, 180.0f), 360.0f), 180.0f);
  t = __fsub_rn(fmodf(__fadd_rn(t, 180.0f), 360.0f), 180.0f);
  out_poses[b*3+0] = x; out_poses[b*3+1] = y; out_poses[b*3+2] = t;
  // x*100/5 -> (x*100)*0.2f under fast-math
  float st0 = __fmul_rn(__fmul_rn(x, 100.0f), 0.2f);
  float st1 = __fmul_rn(__fmul_rn(y, 100.0f), 0.2f);
  float st2 = __fsub_rn(90.0f, t);
  float trad = __fmul_rn(st2, (float)(M_PI / 180.0));
  params[b*4+0] = (float)cos((double)trad);   // c
  params[b*4+1] = (float)sin((double)trad);   // s
  params[b*4+2] = st1;                        // trans[0]
  params[b*4+3] = st0;                        // trans[1]
}

__global__ __launch_bounds__(256) void init_first(int* __restrict__ first) {
  int i = blockIdx.x * blockDim.x + threadIdx.x;
  if (i < BSZ * NVOXB) first[i] = 0x7FFFFFFF;
}

__global__ __launch_bounds__(256) void voxmin_kernel(const float* __restrict__ obs,
                                                     int* __restrict__ first, float rfoc) {
  int gid = blockIdx.x * blockDim.x + threadIdx.x;
  if (gid >= BSZ * NPIX) return;
  int b = gid / NPIX, n = gid % NPIX;
  int r = n / WW, u = n % WW;
  float draw = obs[((size_t)(b*4 + 3) * HH + r) * WW + u];
  PtRes p = compute_pt(draw, u, r, rfoc);
  if (p.valid) atomicMin(&first[b * NVOXB + p.vox], n);
}

__global__ __launch_bounds__(256) void copy_maps(const float* __restrict__ map_last,
                                                 float* __restrict__ out_maps) {
  int i = blockIdx.x * blockDim.x + threadIdx.x;
  if (i < BSZ * 4 * LM * LM) out_maps[i] = map_last[i];
}

// kernel A: coords + rep + maps scatter
__global__ __launch_bounds__(256) void coords_kernel(const float* __restrict__ obs,
                                                     const int* __restrict__ first,
                                                     const float* __restrict__ params,
                                                     float* __restrict__ out, float rfoc) {
  int gid = blockIdx.x * blockDim.x + threadIdx.x;
  if (gid >= BSZ * NPIX) return;
  int b = gid / NPIX, n = gid % NPIX;
  int r = n / WW, u = n % WW;
  float draw = obs[((size_t)(b*4 + 3) * HH + r) * WW + u];
  PtRes p = compute_pt(draw, u, r, rfoc);
  bool rep = p.valid && (first[b * NVOXB + p.vox] == n);

  float c   = params[b*4+0], s = params[b*4+1];
  float tr0 = params[b*4+2], tr1 = params[b*4+3];

  // f32 gemm-style FMA chain (Eigen/XLA-CPU)
  float gcf0 = (float)p.g1, gcf1 = (float)(p.g0 - 50);
  float d0 = fmaf(gcf1, -s, __fmul_rn(gcf0, c));
  float d1 = fmaf(gcf1,  c, __fmul_rn(gcf0, s));
  int gx = (int)rintf(__fadd_rn(d0, tr0));   // np.round = half-even
  int gy = (int)rintf(__fadd_rn(d1, tr1));
  int gz = p.g2 + 8;

  float* nc = out + OFF_COORDS + (size_t)gid * 4;
  if (rep) { nc[0] = (float)b; nc[1] = (float)gx; nc[2] = (float)gy; nc[3] = (float)gz; }
  else     { nc[0] = 0.0f; nc[1] = 0.0f; nc[2] = 0.0f; nc[3] = 0.0f; }

  out[OFF_REP + gid] = rep ? 1.0f : 0.0f;

  if (rep) {
    int xs = min(max(gx, 0), LM - 1);
    int ys = min(max(gy, 0), LM - 1);
    out[OFF_MAPS + ((size_t)(b*4 + 1) * LM + xs) * LM + ys] = 1.0f;
    if (gz >= 13 && gz <= 25)
      out[OFF_MAPS + ((size_t)(b*4 + 0) * LM + xs) * LM + ys] = 1.0f;
  }
}

// kernel B: feats (overwrites the first[] scratch living in the feat region)
__global__ __launch_bounds__(256) void feat_kernel(const float* __restrict__ obs,
                                                   const float* __restrict__ params,
                                                   const float* __restrict__ rep_flags,
                                                   float* __restrict__ out, float rfoc) {
  int gid = blockIdx.x * blockDim.x + threadIdx.x;
  if (gid >= BSZ * NPIX) return;
  int b = gid / NPIX, n = gid % NPIX;
  int r = n / WW, u = n % WW;
  float* fo = out + OFF_FEAT + (size_t)gid * 8;
  bool rep = rep_flags[gid] != 0.0f;
  if (!rep) {
    #pragma unroll
    for (int i = 0; i < 8; ++i) fo[i] = 0.0f;
    return;
  }
  float draw = obs[((size_t)(b*4 + 3) * HH + r) * WW + u];
  PtRes p = compute_pt(draw, u, r, rfoc);
  float c   = params[b*4+0], s = params[b*4+1];
  float tr0 = params[b*4+2], tr1 = params[b*4+3];
  float cf0 = p.depth;
  float cf1 = __fsub_rn(p.X, 2.5f);                 // X + (190-240)*0.05
  float e0 = __fadd_rn(fmaf(cf1, -s, __fmul_rn(cf0, c)), __fmul_rn(tr0, 0.05f));
  float e1 = __fadd_rn(fmaf(cf1,  c, __fmul_rn(cf0, s)), __fmul_rn(tr1, 0.05f));
  float e2 = __fadd_rn(p.Z, 0.4f);
  float R  = obs[((size_t)(b*4 + 0) * HH + r) * WW + u];
  float G  = obs[((size_t)(b*4 + 1) * HH + r) * WW + u];
  float Bv = obs[((size_t)(b*4 + 2) * HH + r) * WW + u];
  fo[0] = e0; fo[1] = e1; fo[2] = e2;
  fo[3] = R; fo[4] = G; fo[5] = Bv; fo[6] = 0.0f; fo[7] = 0.0f;
}

extern "C" void kernel_launch(void* const* d_in, const int* in_sizes, int n_in,
                              void* d_out, int out_size, void* d_ws, size_t ws_size,
                              hipStream_t stream) {
  const float* obs        = (const float*)d_in[0];
  const float* pose_obs   = (const float*)d_in[1];
  const float* poses_last = (const float*)d_in[4];
  const float* map_last   = (const float*)d_in[5];
  float* out = (float*)d_out;

  // big scratch lives INSIDE the feat output region (78.6 MB >= 25.6 MB needed);
  // fully overwritten by feat_kernel afterwards. Only 128 B of d_ws used.
  int*   first  = (int*)(out + OFF_FEAT);
  float* params = (float*)d_ws;   // 32 floats

  // f32 FOC literal (jax weak-typed), then f32 reciprocal (fast-math arcp fold)
  float  focf = (float)((double)WW / 2.0 / tan(39.5 * (M_PI / 180.0)));
  float  rfoc = (float)(1.0 / (double)focf);

  hipLaunchKernelGGL(pose_kernel, dim3(1), dim3(64), 0, stream,
                     pose_obs, poses_last, out + OFF_POSES, params);
  hipLaunchKernelGGL(init_first, dim3((BSZ * NVOXB + 255) / 256), dim3(256), 0, stream, first);
  hipLaunchKernelGGL(voxmin_kernel, dim3((BSZ * NPIX + 255) / 256), dim3(256), 0, stream,
                     obs, first, rfoc);
  hipLaunchKernelGGL(copy_maps, dim3((BSZ * 4 * LM * LM + 255) / 256), dim3(256), 0, stream,
                     map_last, out + OFF_MAPS);
  hipLaunchKernelGGL(coords_kernel, dim3((BSZ * NPIX + 255) / 256), dim3(256), 0, stream,
                     obs, first, params, out, rfoc);
  hipLaunchKernelGGL(feat_kernel, dim3((BSZ * NPIX + 255) / 256), dim3(256), 0, stream,
                     obs, params, out + OFF_REP, out, rfoc);
}

// Round 7
// 167.624 us; speedup vs baseline: 1.0702x; 1.0702x over previous
//
#include <hip/hip_runtime.h>
#include <math.h>

#define BSZ 8
#define HH 480
#define WW 640
#define NPIX (HH*WW)          // 307200
#define VRES 100
#define NZB 80
#define NVOXB (VRES*VRES*NZB) // 800000
#define LM 480

// output layout (flat float32, return order)
#define OFF_COORDS 0LL
#define OFF_FEAT   9830400LL                     // 8*307200*4
#define OFF_MAPS   29491200LL                    // + 8*307200*8
#define OFF_POSES  36864000LL                    // + 8*4*480*480
#define OFF_REP    36864024LL                    // + 24

struct PtRes { float depth, X, Z; int g0, g1, g2, vox; bool valid; };

// PASSING arithmetic chain (round 6) — do not perturb:
// fast-math reciprocal multiplies: /100 -> *0.01f, /FOC -> *f32(1/FOC), /0.05 -> *20.0f
__device__ __forceinline__ PtRes compute_pt(float draw, int u, int r, float rfoc) {
  PtRes p;
  p.depth = __fmul_rn(draw, 0.01f);
  p.X = __fadd_rn(__fmul_rn(__fmul_rn(__fsub_rn((float)u, 319.5f), p.depth), rfoc), 2.5f);
  p.Z = __fadd_rn(__fmul_rn(__fmul_rn(__fsub_rn((float)(HH - 1 - r), 239.5f), p.depth), rfoc), 0.88f);
  p.valid = (p.X > 0.0f) & (p.X < 5.0f) & (p.depth > 0.0f) & (p.depth < 5.0f)
          & (p.Z > -0.4f) & (p.Z < 3.6f);
  p.g0 = (int)floorf(__fmul_rn(p.X, 20.0f));
  p.g1 = (int)floorf(__fmul_rn(p.depth, 20.0f));
  p.g2 = (int)floorf(__fmul_rn(p.Z, 20.0f));
  int c0 = min(max(p.g0, 0), VRES - 1);
  int c1 = min(max(p.g1, 0), VRES - 1);
  int c2 = min(max(p.g2 + 8, 0), NZB - 1);
  p.vox = (c0 * VRES + c1) * NZB + c2;
  return p;
}

__global__ void pose_kernel(const float* __restrict__ pose_obs,
                            const float* __restrict__ poses_last,
                            float* __restrict__ out_poses,
                            float* __restrict__ params) {
  int b = threadIdx.x;
  if (b >= BSZ) return;
  float p0 = poses_last[b*3+0], p1 = poses_last[b*3+1], p2 = poses_last[b*3+2];
  float r0 = pose_obs[b*3+0],  r1 = pose_obs[b*3+1],  r2 = pose_obs[b*3+2];
  const float DEGf = (float)57.29577951308232;
  float thf = __fmul_rn(p2, (float)0.017453292519943295);
  float sth = (float)sin((double)thf);
  float cth = (float)cos((double)thf);
  float y = __fadd_rn(__fadd_rn(p1, __fmul_rn(r0, sth)), __fmul_rn(r1, cth));
  float x = __fsub_rn(__fadd_rn(p0, __fmul_rn(r0, cth)), __fmul_rn(r1, sth));
  float t = __fadd_rn(p2, __fmul_rn(r2, DEGf));
  t = __fadd_rn(fmodf(__fsub_rn(t, 180.0f), 360.0f), 180.0f);
  t = __fsub_rn(fmodf(__fadd_rn(t, 180.0f), 360.0f), 180.0f);
  out_poses[b*3+0] = x; out_poses[b*3+1] = y; out_poses[b*3+2] = t;
  float st0 = __fmul_rn(__fmul_rn(x, 100.0f), 0.2f);
  float st1 = __fmul_rn(__fmul_rn(y, 100.0f), 0.2f);
  float st2 = __fsub_rn(90.0f, t);
  float trad = __fmul_rn(st2, (float)(M_PI / 180.0));
  params[b*4+0] = (float)cos((double)trad);   // c
  params[b*4+1] = (float)sin((double)trad);   // s
  params[b*4+2] = st1;                        // trans[0]
  params[b*4+3] = st0;                        // trans[1]
}

// fused init(first)=INT_MAX + copy(maps) — all 16B vector ops
#define NI (BSZ * NVOXB / 4)        // 1,600,000 int4 stores
#define NC (BSZ * 4 * LM * LM / 4)  // 1,843,200 float4 copies
__global__ __launch_bounds__(256) void init_copy_kernel(int* __restrict__ first,
                                                        const float* __restrict__ map_last,
                                                        float* __restrict__ out_maps) {
  int i = blockIdx.x * blockDim.x + threadIdx.x;
  if (i < NI) {
    *(int4*)(first + (size_t)i * 4) = make_int4(0x7FFFFFFF, 0x7FFFFFFF, 0x7FFFFFFF, 0x7FFFFFFF);
  } else {
    int j = i - NI;
    if (j < NC)
      *(float4*)(out_maps + (size_t)j * 4) = *(const float4*)(map_last + (size_t)j * 4);
  }
}

// 8 pixels/thread: 8 independent atomics in flight per lane (latency hiding)
#define VPT 8
__global__ __launch_bounds__(256) void voxmin8_kernel(const float* __restrict__ obs,
                                                      int* __restrict__ first, float rfoc) {
  int gid = blockIdx.x * blockDim.x + threadIdx.x;
  if (gid >= BSZ * (NPIX / VPT)) return;
  int b = gid / (NPIX / VPT), t = gid % (NPIX / VPT);
  int n0 = t * VPT;
  int r = n0 / WW, u0 = n0 % WW;              // 8 | WW: all 8 pixels same row
  const float* rowp = obs + ((size_t)(b*4 + 3) * HH + r) * WW + u0;
  float4 da = *(const float4*)(rowp);
  float4 db = *(const float4*)(rowp + 4);
  float dv[VPT] = {da.x, da.y, da.z, da.w, db.x, db.y, db.z, db.w};
  int* fb = first + b * NVOXB;
  #pragma unroll
  for (int k = 0; k < VPT; ++k) {
    PtRes p = compute_pt(dv[k], u0 + k, r, rfoc);
    if (p.valid) atomicMin(&fb[p.vox], n0 + k);
  }
}

// fused coords + rep + maps-scatter + feats (single pass; first[] in d_ws)
__global__ __launch_bounds__(256) void fused_kernel(const float* __restrict__ obs,
                                                    const int* __restrict__ first,
                                                    const float* __restrict__ params,
                                                    float* __restrict__ out, float rfoc) {
  int gid = blockIdx.x * blockDim.x + threadIdx.x;
  if (gid >= BSZ * NPIX) return;
  int b = gid / NPIX, n = gid % NPIX;
  int r = n / WW, u = n % WW;
  float draw = obs[((size_t)(b*4 + 3) * HH + r) * WW + u];
  PtRes p = compute_pt(draw, u, r, rfoc);
  bool rep = p.valid && (first[b * NVOXB + p.vox] == n);

  float c   = params[b*4+0], s = params[b*4+1];
  float tr0 = params[b*4+2], tr1 = params[b*4+3];

  float gcf0 = (float)p.g1, gcf1 = (float)(p.g0 - 50);
  float d0 = fmaf(gcf1, -s, __fmul_rn(gcf0, c));
  float d1 = fmaf(gcf1,  c, __fmul_rn(gcf0, s));
  int gx = (int)rintf(__fadd_rn(d0, tr0));
  int gy = (int)rintf(__fadd_rn(d1, tr1));
  int gz = p.g2 + 8;

  float4 ncv = rep ? make_float4((float)b, (float)gx, (float)gy, (float)gz)
                   : make_float4(0.f, 0.f, 0.f, 0.f);
  *(float4*)(out + OFF_COORDS + (size_t)gid * 4) = ncv;
  out[OFF_REP + gid] = rep ? 1.0f : 0.0f;

  float4 f0 = make_float4(0.f, 0.f, 0.f, 0.f);
  float4 f1 = make_float4(0.f, 0.f, 0.f, 0.f);
  if (rep) {
    float cf0 = p.depth;
    float cf1 = __fsub_rn(p.X, 2.5f);
    float e0 = __fadd_rn(fmaf(cf1, -s, __fmul_rn(cf0, c)), __fmul_rn(tr0, 0.05f));
    float e1 = __fadd_rn(fmaf(cf1,  c, __fmul_rn(cf0, s)), __fmul_rn(tr1, 0.05f));
    float e2 = __fadd_rn(p.Z, 0.4f);
    float R  = obs[((size_t)(b*4 + 0) * HH + r) * WW + u];
    float G  = obs[((size_t)(b*4 + 1) * HH + r) * WW + u];
    float Bv = obs[((size_t)(b*4 + 2) * HH + r) * WW + u];
    f0 = make_float4(e0, e1, e2, R);
    f1 = make_float4(G, Bv, 0.f, 0.f);
  }
  *(float4*)(out + OFF_FEAT + (size_t)gid * 8)     = f0;
  *(float4*)(out + OFF_FEAT + (size_t)gid * 8 + 4) = f1;

  if (rep) {
    int xs = min(max(gx, 0), LM - 1);
    int ys = min(max(gy, 0), LM - 1);
    out[OFF_MAPS + ((size_t)(b*4 + 1) * LM + xs) * LM + ys] = 1.0f;
    if (gz >= 13 && gz <= 25)
      out[OFF_MAPS + ((size_t)(b*4 + 0) * LM + xs) * LM + ys] = 1.0f;
  }
}

// fallback pair (first[] aliased into feat region, as in round 6)
__global__ __launch_bounds__(256) void coords_kernel(const float* __restrict__ obs,
                                                     const int* __restrict__ first,
                                                     const float* __restrict__ params,
                                                     float* __restrict__ out, float rfoc) {
  int gid = blockIdx.x * blockDim.x + threadIdx.x;
  if (gid >= BSZ * NPIX) return;
  int b = gid / NPIX, n = gid % NPIX;
  int r = n / WW, u = n % WW;
  float draw = obs[((size_t)(b*4 + 3) * HH + r) * WW + u];
  PtRes p = compute_pt(draw, u, r, rfoc);
  bool rep = p.valid && (first[b * NVOXB + p.vox] == n);
  float c   = params[b*4+0], s = params[b*4+1];
  float tr0 = params[b*4+2], tr1 = params[b*4+3];
  float gcf0 = (float)p.g1, gcf1 = (float)(p.g0 - 50);
  float d0 = fmaf(gcf1, -s, __fmul_rn(gcf0, c));
  float d1 = fmaf(gcf1,  c, __fmul_rn(gcf0, s));
  int gx = (int)rintf(__fadd_rn(d0, tr0));
  int gy = (int)rintf(__fadd_rn(d1, tr1));
  int gz = p.g2 + 8;
  float4 ncv = rep ? make_float4((float)b, (float)gx, (float)gy, (float)gz)
                   : make_float4(0.f, 0.f, 0.f, 0.f);
  *(float4*)(out + OFF_COORDS + (size_t)gid * 4) = ncv;
  out[OFF_REP + gid] = rep ? 1.0f : 0.0f;
  if (rep) {
    int xs = min(max(gx, 0), LM - 1);
    int ys = min(max(gy, 0), LM - 1);
    out[OFF_MAPS + ((size_t)(b*4 + 1) * LM + xs) * LM + ys] = 1.0f;
    if (gz >= 13 && gz <= 25)
      out[OFF_MAPS + ((size_t)(b*4 + 0) * LM + xs) * LM + ys] = 1.0f;
  }
}

__global__ __launch_bounds__(256) void feat_kernel(const float* __restrict__ obs,
                                                   const float* __restrict__ params,
                                                   const float* __restrict__ rep_flags,
                                                   float* __restrict__ out, float rfoc) {
  int gid = blockIdx.x * blockDim.x + threadIdx.x;
  if (gid >= BSZ * NPIX) return;
  int b = gid / NPIX, n = gid % NPIX;
  int r = n / WW, u = n % WW;
  bool rep = rep_flags[gid] != 0.0f;
  float4 f0 = make_float4(0.f, 0.f, 0.f, 0.f);
  float4 f1 = make_float4(0.f, 0.f, 0.f, 0.f);
  if (rep) {
    float draw = obs[((size_t)(b*4 + 3) * HH + r) * WW + u];
    PtRes p = compute_pt(draw, u, r, rfoc);
    float c   = params[b*4+0], s = params[b*4+1];
    float tr0 = params[b*4+2], tr1 = params[b*4+3];
    float cf0 = p.depth;
    float cf1 = __fsub_rn(p.X, 2.5f);
    float e0 = __fadd_rn(fmaf(cf1, -s, __fmul_rn(cf0, c)), __fmul_rn(tr0, 0.05f));
    float e1 = __fadd_rn(fmaf(cf1,  c, __fmul_rn(cf0, s)), __fmul_rn(tr1, 0.05f));
    float e2 = __fadd_rn(p.Z, 0.4f);
    float R  = obs[((size_t)(b*4 + 0) * HH + r) * WW + u];
    float G  = obs[((size_t)(b*4 + 1) * HH + r) * WW + u];
    float Bv = obs[((size_t)(b*4 + 2) * HH + r) * WW + u];
    f0 = make_float4(e0, e1, e2, R);
    f1 = make_float4(G, Bv, 0.f, 0.f);
  }
  *(float4*)(out + OFF_FEAT + (size_t)gid * 8)     = f0;
  *(float4*)(out + OFF_FEAT + (size_t)gid * 8 + 4) = f1;
}

extern "C" void kernel_launch(void* const* d_in, const int* in_sizes, int n_in,
                              void* d_out, int out_size, void* d_ws, size_t ws_size,
                              hipStream_t stream) {
  const float* obs        = (const float*)d_in[0];
  const float* pose_obs   = (const float*)d_in[1];
  const float* poses_last = (const float*)d_in[4];
  const float* map_last   = (const float*)d_in[5];
  float* out = (float*)d_out;

  const size_t FIRST_BYTES = (size_t)BSZ * NVOXB * sizeof(int);   // 25.6 MB
  bool use_ws = ws_size >= FIRST_BYTES + 256;
  float* params = (float*)d_ws;  // 128 B
  int*   first  = use_ws ? (int*)((char*)d_ws + 256) : (int*)(out + OFF_FEAT);

  float focf = (float)((double)WW / 2.0 / tan(39.5 * (M_PI / 180.0)));
  float rfoc = (float)(1.0 / (double)focf);

  hipLaunchKernelGGL(pose_kernel, dim3(1), dim3(64), 0, stream,
                     pose_obs, poses_last, out + OFF_POSES, params);
  hipLaunchKernelGGL(init_copy_kernel, dim3((NI + NC + 255) / 256), dim3(256), 0, stream,
                     first, map_last, out + OFF_MAPS);
  hipLaunchKernelGGL(voxmin8_kernel, dim3((BSZ * (NPIX / VPT) + 255) / 256), dim3(256), 0, stream,
                     obs, first, rfoc);
  if (use_ws) {
    hipLaunchKernelGGL(fused_kernel, dim3((BSZ * NPIX + 255) / 256), dim3(256), 0, stream,
                       obs, first, params, out, rfoc);
  } else {
    hipLaunchKernelGGL(coords_kernel, dim3((BSZ * NPIX + 255) / 256), dim3(256), 0, stream,
                       obs, first, params, out, rfoc);
    hipLaunchKernelGGL(feat_kernel, dim3((BSZ * NPIX + 255) / 256), dim3(256), 0, stream,
                       obs, params, out + OFF_REP, out, rfoc);
  }
}

// Round 9
// 164.602 us; speedup vs baseline: 1.0899x; 1.0184x over previous
//
#include <hip/hip_runtime.h>
#include <math.h>

#define BSZ 8
#define HH 480
#define WW 640
#define NPIX (HH*WW)          // 307200
#define VRES 100
#define NZB 80
#define NVOXB (VRES*VRES*NZB) // 800000
#define LM 480

// output layout (flat float32, return order)
#define OFF_COORDS 0LL
#define OFF_FEAT   9830400LL                     // 8*307200*4
#define OFF_MAPS   29491200LL                    // + 8*307200*8
#define OFF_POSES  36864000LL                    // + 8*4*480*480
#define OFF_REP    36864024LL                    // + 24

typedef float  fx4 __attribute__((ext_vector_type(4)));   // NT-store-compatible

struct PtRes { float depth, X, Z; int g0, g1, g2, vox; bool valid; };

// locality-optimized voxel id: (c2, c0) near-constant per wave, c1 minor dim
__device__ __forceinline__ int voxid(int c0, int c1, int c2) {
  return (c2 * VRES + c0) * VRES + c1;
}

// PASSING arithmetic chain (round 6) — do not perturb:
// fast-math reciprocal multiplies: /100 -> *0.01f, /FOC -> *f32(1/FOC), /0.05 -> *20.0f
__device__ __forceinline__ PtRes compute_pt(float draw, int u, int r, float rfoc) {
  PtRes p;
  p.depth = __fmul_rn(draw, 0.01f);
  p.X = __fadd_rn(__fmul_rn(__fmul_rn(__fsub_rn((float)u, 319.5f), p.depth), rfoc), 2.5f);
  p.Z = __fadd_rn(__fmul_rn(__fmul_rn(__fsub_rn((float)(HH - 1 - r), 239.5f), p.depth), rfoc), 0.88f);
  p.valid = (p.X > 0.0f) & (p.X < 5.0f) & (p.depth > 0.0f) & (p.depth < 5.0f)
          & (p.Z > -0.4f) & (p.Z < 3.6f);
  p.g0 = (int)floorf(__fmul_rn(p.X, 20.0f));
  p.g1 = (int)floorf(__fmul_rn(p.depth, 20.0f));
  p.g2 = (int)floorf(__fmul_rn(p.Z, 20.0f));
  int c0 = min(max(p.g0, 0), VRES - 1);
  int c1 = min(max(p.g1, 0), VRES - 1);
  int c2 = min(max(p.g2 + 8, 0), NZB - 1);
  p.vox = voxid(c0, c1, c2);
  return p;
}

__global__ void pose_kernel(const float* __restrict__ pose_obs,
                            const float* __restrict__ poses_last,
                            float* __restrict__ out_poses,
                            float* __restrict__ params) {
  int b = threadIdx.x;
  if (b >= BSZ) return;
  float p0 = poses_last[b*3+0], p1 = poses_last[b*3+1], p2 = poses_last[b*3+2];
  float r0 = pose_obs[b*3+0],  r1 = pose_obs[b*3+1],  r2 = pose_obs[b*3+2];
  const float DEGf = (float)57.29577951308232;
  float thf = __fmul_rn(p2, (float)0.017453292519943295);
  float sth = (float)sin((double)thf);
  float cth = (float)cos((double)thf);
  float y = __fadd_rn(__fadd_rn(p1, __fmul_rn(r0, sth)), __fmul_rn(r1, cth));
  float x = __fsub_rn(__fadd_rn(p0, __fmul_rn(r0, cth)), __fmul_rn(r1, sth));
  float t = __fadd_rn(p2, __fmul_rn(r2, DEGf));
  t = __fadd_rn(fmodf(__fsub_rn(t, 180.0f), 360.0f), 180.0f);
  t = __fsub_rn(fmodf(__fadd_rn(t, 180.0f), 360.0f), 180.0f);
  out_poses[b*3+0] = x; out_poses[b*3+1] = y; out_poses[b*3+2] = t;
  float st0 = __fmul_rn(__fmul_rn(x, 100.0f), 0.2f);
  float st1 = __fmul_rn(__fmul_rn(y, 100.0f), 0.2f);
  float st2 = __fsub_rn(90.0f, t);
  float trad = __fmul_rn(st2, (float)(M_PI / 180.0));
  params[b*4+0] = (float)cos((double)trad);   // c
  params[b*4+1] = (float)sin((double)trad);   // s
  params[b*4+2] = st1;                        // trans[0]
  params[b*4+3] = st0;                        // trans[1]
}

#define NI (BSZ * NVOXB / 4)        // 1,600,000 int4 stores
__global__ __launch_bounds__(256) void init_first(int* __restrict__ first) {
  int i = blockIdx.x * blockDim.x + threadIdx.x;
  if (i < NI)
    *(int4*)(first + (size_t)i * 4) = make_int4(0x7FFFFFFF, 0x7FFFFFFF, 0x7FFFFFFF, 0x7FFFFFFF);
}

#define VPT 8
__global__ __launch_bounds__(256) void voxmin8_kernel(const float* __restrict__ obs,
                                                      int* __restrict__ first, float rfoc) {
  int gid = blockIdx.x * blockDim.x + threadIdx.x;
  if (gid >= BSZ * (NPIX / VPT)) return;
  int b = gid / (NPIX / VPT), t = gid % (NPIX / VPT);
  int n0 = t * VPT;
  int r = n0 / WW, u0 = n0 % WW;              // 8 | WW: all 8 pixels same row
  const float* rowp = obs + ((size_t)(b*4 + 3) * HH + r) * WW + u0;
  float4 da = *(const float4*)(rowp);
  float4 db = *(const float4*)(rowp + 4);
  float dv[VPT] = {da.x, da.y, da.z, da.w, db.x, db.y, db.z, db.w};
  int* fb = first + b * NVOXB;
  #pragma unroll
  for (int k = 0; k < VPT; ++k) {
    PtRes p = compute_pt(dv[k], u0 + k, r, rfoc);
    if (p.valid) atomicMin(&fb[p.vox], n0 + k);
  }
}

// fused coords + rep + feats (reads first[] which lives in the MAPS region;
// does NOT write maps — scatter deferred to after copy_maps)
__global__ __launch_bounds__(256) void fused_kernel(const float* __restrict__ obs,
                                                    const int* __restrict__ first,
                                                    const float* __restrict__ params,
                                                    float* __restrict__ out, float rfoc) {
  int gid = blockIdx.x * blockDim.x + threadIdx.x;
  if (gid >= BSZ * NPIX) return;
  int b = gid / NPIX, n = gid % NPIX;
  int r = n / WW, u = n % WW;
  float draw = obs[((size_t)(b*4 + 3) * HH + r) * WW + u];
  PtRes p = compute_pt(draw, u, r, rfoc);
  bool rep = p.valid && (first[b * NVOXB + p.vox] == n);

  float c   = params[b*4+0], s = params[b*4+1];
  float tr0 = params[b*4+2], tr1 = params[b*4+3];

  float gcf0 = (float)p.g1, gcf1 = (float)(p.g0 - 50);
  float d0 = fmaf(gcf1, -s, __fmul_rn(gcf0, c));
  float d1 = fmaf(gcf1,  c, __fmul_rn(gcf0, s));
  int gx = (int)rintf(__fadd_rn(d0, tr0));
  int gy = (int)rintf(__fadd_rn(d1, tr1));
  int gz = p.g2 + 8;

  fx4 ncv = rep ? (fx4){(float)b, (float)gx, (float)gy, (float)gz}
                : (fx4){0.f, 0.f, 0.f, 0.f};
  __builtin_nontemporal_store(ncv, (fx4*)(out + OFF_COORDS + (size_t)gid * 4));
  out[OFF_REP + gid] = rep ? 1.0f : 0.0f;

  fx4 f0 = {0.f, 0.f, 0.f, 0.f};
  fx4 f1 = {0.f, 0.f, 0.f, 0.f};
  if (rep) {
    float cf0 = p.depth;
    float cf1 = __fsub_rn(p.X, 2.5f);
    float e0 = __fadd_rn(fmaf(cf1, -s, __fmul_rn(cf0, c)), __fmul_rn(tr0, 0.05f));
    float e1 = __fadd_rn(fmaf(cf1,  c, __fmul_rn(cf0, s)), __fmul_rn(tr1, 0.05f));
    float e2 = __fadd_rn(p.Z, 0.4f);
    float R  = obs[((size_t)(b*4 + 0) * HH + r) * WW + u];
    float G  = obs[((size_t)(b*4 + 1) * HH + r) * WW + u];
    float Bv = obs[((size_t)(b*4 + 2) * HH + r) * WW + u];
    f0 = (fx4){e0, e1, e2, R};
    f1 = (fx4){G, Bv, 0.f, 0.f};
  }
  __builtin_nontemporal_store(f0, (fx4*)(out + OFF_FEAT + (size_t)gid * 8));
  __builtin_nontemporal_store(f1, (fx4*)(out + OFF_FEAT + (size_t)gid * 8 + 4));
}

#define NC (BSZ * 4 * LM * LM / 4)  // 1,843,200 float4 copies
__global__ __launch_bounds__(256) void copy_maps(const float* __restrict__ map_last,
                                                 float* __restrict__ out_maps) {
  int i = blockIdx.x * blockDim.x + threadIdx.x;
  if (i < NC)
    *(float4*)(out_maps + (size_t)i * 4) = *(const float4*)(map_last + (size_t)i * 4);
}

// scatter 1.0s into maps from the already-written coords+rep outputs
__global__ __launch_bounds__(256) void scatter_maps(const float* __restrict__ out_coords,
                                                    const float* __restrict__ rep_flags,
                                                    float* __restrict__ out_maps) {
  int gid = blockIdx.x * blockDim.x + threadIdx.x;
  if (gid >= BSZ * NPIX) return;
  if (rep_flags[gid] == 0.0f) return;
  int b = gid / NPIX;
  float4 nc = *(const float4*)(out_coords + (size_t)gid * 4);
  int gx = (int)nc.y, gy = (int)nc.z, gz = (int)nc.w;
  int xs = min(max(gx, 0), LM - 1);
  int ys = min(max(gy, 0), LM - 1);
  out_maps[((size_t)(b*4 + 1) * LM + xs) * LM + ys] = 1.0f;
  if (gz >= 13 && gz <= 25)
    out_maps[((size_t)(b*4 + 0) * LM + xs) * LM + ys] = 1.0f;
}

extern "C" void kernel_launch(void* const* d_in, const int* in_sizes, int n_in,
                              void* d_out, int out_size, void* d_ws, size_t ws_size,
                              hipStream_t stream) {
  const float* obs        = (const float*)d_in[0];
  const float* pose_obs   = (const float*)d_in[1];
  const float* poses_last = (const float*)d_in[4];
  const float* map_last   = (const float*)d_in[5];
  float* out = (float*)d_out;

  float* params = (float*)d_ws;                 // 128 B of d_ws only
  int*   first  = (int*)(out + OFF_MAPS);       // scratch in maps region (29.5 >= 25.6 MB)

  float focf = (float)((double)WW / 2.0 / tan(39.5 * (M_PI / 180.0)));
  float rfoc = (float)(1.0 / (double)focf);

  hipLaunchKernelGGL(pose_kernel, dim3(1), dim3(64), 0, stream,
                     pose_obs, poses_last, out + OFF_POSES, params);
  hipLaunchKernelGGL(init_first, dim3((NI + 255) / 256), dim3(256), 0, stream, first);
  hipLaunchKernelGGL(voxmin8_kernel, dim3((BSZ * (NPIX / VPT) + 255) / 256), dim3(256), 0, stream,
                     obs, first, rfoc);
  hipLaunchKernelGGL(fused_kernel, dim3((BSZ * NPIX + 255) / 256), dim3(256), 0, stream,
                     obs, first, params, out, rfoc);
  hipLaunchKernelGGL(copy_maps, dim3((NC + 255) / 256), dim3(256), 0, stream,
                     map_last, out + OFF_MAPS);
  hipLaunchKernelGGL(scatter_maps, dim3((BSZ * NPIX + 255) / 256), dim3(256), 0, stream,
                     out + OFF_COORDS, out + OFF_REP, out + OFF_MAPS);
}

// Round 10
// 151.218 us; speedup vs baseline: 1.1863x; 1.0885x over previous
//
#include <hip/hip_runtime.h>
#include <math.h>

#define BSZ 8
#define HH 480
#define WW 640
#define NPIX (HH*WW)          // 307200
#define VRES 100
#define NZB 80
#define NVOXB (VRES*VRES*NZB) // 800000
#define LM 480

// output layout (flat float32, return order)
#define OFF_COORDS 0LL
#define OFF_FEAT   9830400LL                     // 8*307200*4
#define OFF_MAPS   29491200LL                    // + 8*307200*8
#define OFF_POSES  36864000LL                    // + 8*4*480*480
#define OFF_REP    36864024LL                    // + 24

typedef float fx4 __attribute__((ext_vector_type(4)));

struct PtRes { float depth, X, Z; int g0, g1, g2, vox; bool valid; };

// locality voxel id: (c2, c0) near-constant per wave, c1 minor dim
__device__ __forceinline__ int voxid(int c0, int c1, int c2) {
  return (c2 * VRES + c0) * VRES + c1;
}

// PASSING arithmetic chain (round 6) — do not perturb:
// fast-math reciprocal multiplies: /100 -> *0.01f, /FOC -> *f32(1/FOC), /0.05 -> *20.0f
__device__ __forceinline__ PtRes compute_pt(float draw, int u, int r, float rfoc) {
  PtRes p;
  p.depth = __fmul_rn(draw, 0.01f);
  p.X = __fadd_rn(__fmul_rn(__fmul_rn(__fsub_rn((float)u, 319.5f), p.depth), rfoc), 2.5f);
  p.Z = __fadd_rn(__fmul_rn(__fmul_rn(__fsub_rn((float)(HH - 1 - r), 239.5f), p.depth), rfoc), 0.88f);
  p.valid = (p.X > 0.0f) & (p.X < 5.0f) & (p.depth > 0.0f) & (p.depth < 5.0f)
          & (p.Z > -0.4f) & (p.Z < 3.6f);
  p.g0 = (int)floorf(__fmul_rn(p.X, 20.0f));
  p.g1 = (int)floorf(__fmul_rn(p.depth, 20.0f));
  p.g2 = (int)floorf(__fmul_rn(p.Z, 20.0f));
  int c0 = min(max(p.g0, 0), VRES - 1);
  int c1 = min(max(p.g1, 0), VRES - 1);
  int c2 = min(max(p.g2 + 8, 0), NZB - 1);
  p.vox = voxid(c0, c1, c2);
  return p;
}

__global__ void pose_kernel(const float* __restrict__ pose_obs,
                            const float* __restrict__ poses_last,
                            float* __restrict__ out_poses,
                            float* __restrict__ params) {
  int b = threadIdx.x;
  if (b >= BSZ) return;
  float p0 = poses_last[b*3+0], p1 = poses_last[b*3+1], p2 = poses_last[b*3+2];
  float r0 = pose_obs[b*3+0],  r1 = pose_obs[b*3+1],  r2 = pose_obs[b*3+2];
  const float DEGf = (float)57.29577951308232;
  float thf = __fmul_rn(p2, (float)0.017453292519943295);
  float sth = (float)sin((double)thf);
  float cth = (float)cos((double)thf);
  float y = __fadd_rn(__fadd_rn(p1, __fmul_rn(r0, sth)), __fmul_rn(r1, cth));
  float x = __fsub_rn(__fadd_rn(p0, __fmul_rn(r0, cth)), __fmul_rn(r1, sth));
  float t = __fadd_rn(p2, __fmul_rn(r2, DEGf));
  t = __fadd_rn(fmodf(__fsub_rn(t, 180.0f), 360.0f), 180.0f);
  t = __fsub_rn(fmodf(__fadd_rn(t, 180.0f), 360.0f), 180.0f);
  out_poses[b*3+0] = x; out_poses[b*3+1] = y; out_poses[b*3+2] = t;
  float st0 = __fmul_rn(__fmul_rn(x, 100.0f), 0.2f);
  float st1 = __fmul_rn(__fmul_rn(y, 100.0f), 0.2f);
  float st2 = __fsub_rn(90.0f, t);
  float trad = __fmul_rn(st2, (float)(M_PI / 180.0));
  params[b*4+0] = (float)cos((double)trad);   // c
  params[b*4+1] = (float)sin((double)trad);   // s
  params[b*4+2] = st1;                        // trans[0]
  params[b*4+3] = st0;                        // trans[1]
}

#define VPT 8
// phase 1: racy plain stores — leaves SOME candidate pixel idx in each touched voxel.
// Untouched voxels are never read downstream, so no init pass is needed.
__global__ __launch_bounds__(256) void vox_store(const float* __restrict__ obs,
                                                 int* __restrict__ first, float rfoc) {
  int gid = blockIdx.x * blockDim.x + threadIdx.x;
  if (gid >= BSZ * (NPIX / VPT)) return;
  int b = gid / (NPIX / VPT), t = gid % (NPIX / VPT);
  int n0 = t * VPT;
  int r = n0 / WW, u0 = n0 % WW;
  const float* rowp = obs + ((size_t)(b*4 + 3) * HH + r) * WW + u0;
  float4 da = *(const float4*)(rowp);
  float4 db = *(const float4*)(rowp + 4);
  float dv[VPT] = {da.x, da.y, da.z, da.w, db.x, db.y, db.z, db.w};
  int* fb = first + b * NVOXB;
  #pragma unroll
  for (int k = 0; k < VPT; ++k) {
    PtRes p = compute_pt(dv[k], u0 + k, r, rfoc);
    if (p.valid) fb[p.vox] = n0 + k;
  }
}

// phase 2: refine — only pixels that beat the stored candidate issue a device atomic.
__global__ __launch_bounds__(256) void vox_refine(const float* __restrict__ obs,
                                                  int* __restrict__ first, float rfoc) {
  int gid = blockIdx.x * blockDim.x + threadIdx.x;
  if (gid >= BSZ * (NPIX / VPT)) return;
  int b = gid / (NPIX / VPT), t = gid % (NPIX / VPT);
  int n0 = t * VPT;
  int r = n0 / WW, u0 = n0 % WW;
  const float* rowp = obs + ((size_t)(b*4 + 3) * HH + r) * WW + u0;
  float4 da = *(const float4*)(rowp);
  float4 db = *(const float4*)(rowp + 4);
  float dv[VPT] = {da.x, da.y, da.z, da.w, db.x, db.y, db.z, db.w};
  int* fb = first + b * NVOXB;
  #pragma unroll
  for (int k = 0; k < VPT; ++k) {
    PtRes p = compute_pt(dv[k], u0 + k, r, rfoc);
    if (p.valid) {
      int n = n0 + k;
      if (n < fb[p.vox]) atomicMin(&fb[p.vox], n);
    }
  }
}

// fused coords + rep + feats (reads exact first[] from the MAPS region;
// maps writes deferred until after copy_maps overwrites the scratch)
__global__ __launch_bounds__(256) void fused_kernel(const float* __restrict__ obs,
                                                    const int* __restrict__ first,
                                                    const float* __restrict__ params,
                                                    float* __restrict__ out, float rfoc) {
  int gid = blockIdx.x * blockDim.x + threadIdx.x;
  if (gid >= BSZ * NPIX) return;
  int b = gid / NPIX, n = gid % NPIX;
  int r = n / WW, u = n % WW;
  float draw = obs[((size_t)(b*4 + 3) * HH + r) * WW + u];
  PtRes p = compute_pt(draw, u, r, rfoc);
  bool rep = p.valid && (first[b * NVOXB + p.vox] == n);

  float c   = params[b*4+0], s = params[b*4+1];
  float tr0 = params[b*4+2], tr1 = params[b*4+3];

  float gcf0 = (float)p.g1, gcf1 = (float)(p.g0 - 50);
  float d0 = fmaf(gcf1, -s, __fmul_rn(gcf0, c));
  float d1 = fmaf(gcf1,  c, __fmul_rn(gcf0, s));
  int gx = (int)rintf(__fadd_rn(d0, tr0));
  int gy = (int)rintf(__fadd_rn(d1, tr1));
  int gz = p.g2 + 8;

  fx4 ncv = rep ? (fx4){(float)b, (float)gx, (float)gy, (float)gz}
                : (fx4){0.f, 0.f, 0.f, 0.f};
  __builtin_nontemporal_store(ncv, (fx4*)(out + OFF_COORDS + (size_t)gid * 4));
  out[OFF_REP + gid] = rep ? 1.0f : 0.0f;

  fx4 f0 = {0.f, 0.f, 0.f, 0.f};
  fx4 f1 = {0.f, 0.f, 0.f, 0.f};
  if (rep) {
    float cf0 = p.depth;
    float cf1 = __fsub_rn(p.X, 2.5f);
    float e0 = __fadd_rn(fmaf(cf1, -s, __fmul_rn(cf0, c)), __fmul_rn(tr0, 0.05f));
    float e1 = __fadd_rn(fmaf(cf1,  c, __fmul_rn(cf0, s)), __fmul_rn(tr1, 0.05f));
    float e2 = __fadd_rn(p.Z, 0.4f);
    float R  = obs[((size_t)(b*4 + 0) * HH + r) * WW + u];
    float G  = obs[((size_t)(b*4 + 1) * HH + r) * WW + u];
    float Bv = obs[((size_t)(b*4 + 2) * HH + r) * WW + u];
    f0 = (fx4){e0, e1, e2, R};
    f1 = (fx4){G, Bv, 0.f, 0.f};
  }
  __builtin_nontemporal_store(f0, (fx4*)(out + OFF_FEAT + (size_t)gid * 8));
  __builtin_nontemporal_store(f1, (fx4*)(out + OFF_FEAT + (size_t)gid * 8 + 4));
}

#define NC (BSZ * 4 * LM * LM / 4)  // 1,843,200 float4 copies
__global__ __launch_bounds__(256) void copy_maps(const float* __restrict__ map_last,
                                                 float* __restrict__ out_maps) {
  int i = blockIdx.x * blockDim.x + threadIdx.x;
  if (i < NC)
    *(float4*)(out_maps + (size_t)i * 4) = *(const float4*)(map_last + (size_t)i * 4);
}

// scatter 1.0s into maps from the already-written coords+rep outputs
__global__ __launch_bounds__(256) void scatter_maps(const float* __restrict__ out_coords,
                                                    const float* __restrict__ rep_flags,
                                                    float* __restrict__ out_maps) {
  int gid = blockIdx.x * blockDim.x + threadIdx.x;
  if (gid >= BSZ * NPIX) return;
  if (rep_flags[gid] == 0.0f) return;
  int b = gid / NPIX;
  float4 nc = *(const float4*)(out_coords + (size_t)gid * 4);
  int gx = (int)nc.y, gy = (int)nc.z, gz = (int)nc.w;
  int xs = min(max(gx, 0), LM - 1);
  int ys = min(max(gy, 0), LM - 1);
  out_maps[((size_t)(b*4 + 1) * LM + xs) * LM + ys] = 1.0f;
  if (gz >= 13 && gz <= 25)
    out_maps[((size_t)(b*4 + 0) * LM + xs) * LM + ys] = 1.0f;
}

extern "C" void kernel_launch(void* const* d_in, const int* in_sizes, int n_in,
                              void* d_out, int out_size, void* d_ws, size_t ws_size,
                              hipStream_t stream) {
  const float* obs        = (const float*)d_in[0];
  const float* pose_obs   = (const float*)d_in[1];
  const float* poses_last = (const float*)d_in[4];
  const float* map_last   = (const float*)d_in[5];
  float* out = (float*)d_out;

  float* params = (float*)d_ws;                 // 128 B of d_ws only
  int*   first  = (int*)(out + OFF_MAPS);       // scratch in maps region (29.5 >= 25.6 MB)

  float focf = (float)((double)WW / 2.0 / tan(39.5 * (M_PI / 180.0)));
  float rfoc = (float)(1.0 / (double)focf);

  int vox_blocks = (BSZ * (NPIX / VPT) + 255) / 256;

  hipLaunchKernelGGL(pose_kernel, dim3(1), dim3(64), 0, stream,
                     pose_obs, poses_last, out + OFF_POSES, params);
  hipLaunchKernelGGL(vox_store, dim3(vox_blocks), dim3(256), 0, stream, obs, first, rfoc);
  hipLaunchKernelGGL(vox_refine, dim3(vox_blocks), dim3(256), 0, stream, obs, first, rfoc);
  hipLaunchKernelGGL(fused_kernel, dim3((BSZ * NPIX + 255) / 256), dim3(256), 0, stream,
                     obs, first, params, out, rfoc);
  hipLaunchKernelGGL(copy_maps, dim3((NC + 255) / 256), dim3(256), 0, stream,
                     map_last, out + OFF_MAPS);
  hipLaunchKernelGGL(scatter_maps, dim3((BSZ * NPIX + 255) / 256), dim3(256), 0, stream,
                     out + OFF_COORDS, out + OFF_REP, out + OFF_MAPS);
}

// Round 11
// 132.817 us; speedup vs baseline: 1.3507x; 1.1385x over previous
//
#include <hip/hip_runtime.h>
#include <math.h>

#define BSZ 8
#define HH 480
#define WW 640
#define NPIX (HH*WW)          // 307200
#define VRES 100
#define NZB 80
#define NVOXB (VRES*VRES*NZB) // 800000
#define LM 480

// output layout (flat float32, return order)
#define OFF_COORDS 0LL
#define OFF_FEAT   9830400LL                     // 8*307200*4
#define OFF_MAPS   29491200LL                    // + 8*307200*8
#define OFF_POSES  36864000LL                    // + 8*4*480*480
#define OFF_REP    36864024LL                    // + 24

typedef float fx4 __attribute__((ext_vector_type(4)));

struct PtRes { float depth, X, Z; int g0, g1, g2, vox; bool valid; };

// locality voxel id: (c2, c0) near-constant per wave, c1 minor dim
__device__ __forceinline__ int voxid(int c0, int c1, int c2) {
  return (c2 * VRES + c0) * VRES + c1;
}

// PASSING arithmetic chain (round 6) — do not perturb:
// fast-math reciprocal multiplies: /100 -> *0.01f, /FOC -> *f32(1/FOC), /0.05 -> *20.0f
__device__ __forceinline__ PtRes compute_pt(float draw, int u, int r, float rfoc) {
  PtRes p;
  p.depth = __fmul_rn(draw, 0.01f);
  p.X = __fadd_rn(__fmul_rn(__fmul_rn(__fsub_rn((float)u, 319.5f), p.depth), rfoc), 2.5f);
  p.Z = __fadd_rn(__fmul_rn(__fmul_rn(__fsub_rn((float)(HH - 1 - r), 239.5f), p.depth), rfoc), 0.88f);
  p.valid = (p.X > 0.0f) & (p.X < 5.0f) & (p.depth > 0.0f) & (p.depth < 5.0f)
          & (p.Z > -0.4f) & (p.Z < 3.6f);
  p.g0 = (int)floorf(__fmul_rn(p.X, 20.0f));
  p.g1 = (int)floorf(__fmul_rn(p.depth, 20.0f));
  p.g2 = (int)floorf(__fmul_rn(p.Z, 20.0f));
  int c0 = min(max(p.g0, 0), VRES - 1);
  int c1 = min(max(p.g1, 0), VRES - 1);
  int c2 = min(max(p.g2 + 8, 0), NZB - 1);
  p.vox = voxid(c0, c1, c2);
  return p;
}

__global__ void pose_kernel(const float* __restrict__ pose_obs,
                            const float* __restrict__ poses_last,
                            float* __restrict__ out_poses,
                            float* __restrict__ params) {
  int b = threadIdx.x;
  if (b >= BSZ) return;
  float p0 = poses_last[b*3+0], p1 = poses_last[b*3+1], p2 = poses_last[b*3+2];
  float r0 = pose_obs[b*3+0],  r1 = pose_obs[b*3+1],  r2 = pose_obs[b*3+2];
  const float DEGf = (float)57.29577951308232;
  float thf = __fmul_rn(p2, (float)0.017453292519943295);
  float sth = (float)sin((double)thf);
  float cth = (float)cos((double)thf);
  float y = __fadd_rn(__fadd_rn(p1, __fmul_rn(r0, sth)), __fmul_rn(r1, cth));
  float x = __fsub_rn(__fadd_rn(p0, __fmul_rn(r0, cth)), __fmul_rn(r1, sth));
  float t = __fadd_rn(p2, __fmul_rn(r2, DEGf));
  t = __fadd_rn(fmodf(__fsub_rn(t, 180.0f), 360.0f), 180.0f);
  t = __fsub_rn(fmodf(__fadd_rn(t, 180.0f), 360.0f), 180.0f);
  out_poses[b*3+0] = x; out_poses[b*3+1] = y; out_poses[b*3+2] = t;
  float st0 = __fmul_rn(__fmul_rn(x, 100.0f), 0.2f);
  float st1 = __fmul_rn(__fmul_rn(y, 100.0f), 0.2f);
  float st2 = __fsub_rn(90.0f, t);
  float trad = __fmul_rn(st2, (float)(M_PI / 180.0));
  params[b*4+0] = (float)cos((double)trad);   // c
  params[b*4+1] = (float)sin((double)trad);   // s
  params[b*4+2] = st1;                        // trans[0]
  params[b*4+3] = st0;                        // trans[1]
}

#define VPT 8
#define VOXWORK (BSZ * (NPIX / VPT))   // 307200 threads
#define NC (BSZ * 4 * LM * LM / 4)     // 1,843,200 float4 copies

// phase 1: racy plain stores — leaves SOME candidate pixel idx in each touched
// voxel (untouched voxels never read downstream; no init needed). Exactness is
// restored by the refine pass, so the race outcome doesn't affect the result.
__global__ __launch_bounds__(256) void vox_store(const float* __restrict__ obs,
                                                 int* __restrict__ first, float rfoc) {
  int gid = blockIdx.x * blockDim.x + threadIdx.x;
  if (gid >= VOXWORK) return;
  int b = gid / (NPIX / VPT), t = gid % (NPIX / VPT);
  int n0 = t * VPT;
  int r = n0 / WW, u0 = n0 % WW;
  const float* rowp = obs + ((size_t)(b*4 + 3) * HH + r) * WW + u0;
  float4 da = *(const float4*)(rowp);
  float4 db = *(const float4*)(rowp + 4);
  float dv[VPT] = {da.x, da.y, da.z, da.w, db.x, db.y, db.z, db.w};
  int* fb = first + b * NVOXB;
  #pragma unroll
  for (int k = 0; k < VPT; ++k) {
    PtRes p = compute_pt(dv[k], u0 + k, r, rfoc);
    if (p.valid) fb[p.vox] = n0 + k;
  }
}

// phase 2 (+ optional fused map copy in the same launch):
// only pixels beating the stored candidate issue a device atomic.
__global__ __launch_bounds__(256) void vox_refine_copy(const float* __restrict__ obs,
                                                       int* __restrict__ first, float rfoc,
                                                       const float* __restrict__ map_last,
                                                       float* __restrict__ out_maps,
                                                       int do_copy) {
  int gid = blockIdx.x * blockDim.x + threadIdx.x;
  if (gid < VOXWORK) {
    int b = gid / (NPIX / VPT), t = gid % (NPIX / VPT);
    int n0 = t * VPT;
    int r = n0 / WW, u0 = n0 % WW;
    const float* rowp = obs + ((size_t)(b*4 + 3) * HH + r) * WW + u0;
    float4 da = *(const float4*)(rowp);
    float4 db = *(const float4*)(rowp + 4);
    float dv[VPT] = {da.x, da.y, da.z, da.w, db.x, db.y, db.z, db.w};
    int* fb = first + b * NVOXB;
    #pragma unroll
    for (int k = 0; k < VPT; ++k) {
      PtRes p = compute_pt(dv[k], u0 + k, r, rfoc);
      if (p.valid) {
        int n = n0 + k;
        if (n < fb[p.vox]) atomicMin(&fb[p.vox], n);
      }
    }
  } else if (do_copy) {
    int j = gid - VOXWORK;
    if (j < NC)
      *(float4*)(out_maps + (size_t)j * 4) = *(const float4*)(map_last + (size_t)j * 4);
  }
}

// fused: coords + rep + feats (+ maps scatter when first[] is NOT aliased there)
__global__ __launch_bounds__(256) void fused_kernel(const float* __restrict__ obs,
                                                    const int* __restrict__ first,
                                                    const float* __restrict__ params,
                                                    float* __restrict__ out, float rfoc,
                                                    int write_maps) {
  int gid = blockIdx.x * blockDim.x + threadIdx.x;
  if (gid >= BSZ * NPIX) return;
  int b = gid / NPIX, n = gid % NPIX;
  int r = n / WW, u = n % WW;
  float draw = obs[((size_t)(b*4 + 3) * HH + r) * WW + u];
  PtRes p = compute_pt(draw, u, r, rfoc);
  bool rep = p.valid && (first[b * NVOXB + p.vox] == n);

  float c   = params[b*4+0], s = params[b*4+1];
  float tr0 = params[b*4+2], tr1 = params[b*4+3];

  float gcf0 = (float)p.g1, gcf1 = (float)(p.g0 - 50);
  float d0 = fmaf(gcf1, -s, __fmul_rn(gcf0, c));
  float d1 = fmaf(gcf1,  c, __fmul_rn(gcf0, s));
  int gx = (int)rintf(__fadd_rn(d0, tr0));
  int gy = (int)rintf(__fadd_rn(d1, tr1));
  int gz = p.g2 + 8;

  fx4 ncv = rep ? (fx4){(float)b, (float)gx, (float)gy, (float)gz}
                : (fx4){0.f, 0.f, 0.f, 0.f};
  __builtin_nontemporal_store(ncv, (fx4*)(out + OFF_COORDS + (size_t)gid * 4));
  out[OFF_REP + gid] = rep ? 1.0f : 0.0f;

  fx4 f0 = {0.f, 0.f, 0.f, 0.f};
  fx4 f1 = {0.f, 0.f, 0.f, 0.f};
  if (rep) {
    float cf0 = p.depth;
    float cf1 = __fsub_rn(p.X, 2.5f);
    float e0 = __fadd_rn(fmaf(cf1, -s, __fmul_rn(cf0, c)), __fmul_rn(tr0, 0.05f));
    float e1 = __fadd_rn(fmaf(cf1,  c, __fmul_rn(cf0, s)), __fmul_rn(tr1, 0.05f));
    float e2 = __fadd_rn(p.Z, 0.4f);
    float R  = obs[((size_t)(b*4 + 0) * HH + r) * WW + u];
    float G  = obs[((size_t)(b*4 + 1) * HH + r) * WW + u];
    float Bv = obs[((size_t)(b*4 + 2) * HH + r) * WW + u];
    f0 = (fx4){e0, e1, e2, R};
    f1 = (fx4){G, Bv, 0.f, 0.f};
  }
  __builtin_nontemporal_store(f0, (fx4*)(out + OFF_FEAT + (size_t)gid * 8));
  __builtin_nontemporal_store(f1, (fx4*)(out + OFF_FEAT + (size_t)gid * 8 + 4));

  if (write_maps && rep) {
    int xs = min(max(gx, 0), LM - 1);
    int ys = min(max(gy, 0), LM - 1);
    out[OFF_MAPS + ((size_t)(b*4 + 1) * LM + xs) * LM + ys] = 1.0f;
    if (gz >= 13 && gz <= 25)
      out[OFF_MAPS + ((size_t)(b*4 + 0) * LM + xs) * LM + ys] = 1.0f;
  }
}

__global__ __launch_bounds__(256) void copy_maps(const float* __restrict__ map_last,
                                                 float* __restrict__ out_maps) {
  int i = blockIdx.x * blockDim.x + threadIdx.x;
  if (i < NC)
    *(float4*)(out_maps + (size_t)i * 4) = *(const float4*)(map_last + (size_t)i * 4);
}

// fallback-only: scatter from already-written coords+rep
__global__ __launch_bounds__(256) void scatter_maps(const float* __restrict__ out_coords,
                                                    const float* __restrict__ rep_flags,
                                                    float* __restrict__ out_maps) {
  int gid = blockIdx.x * blockDim.x + threadIdx.x;
  if (gid >= BSZ * NPIX) return;
  if (rep_flags[gid] == 0.0f) return;
  int b = gid / NPIX;
  float4 nc = *(const float4*)(out_coords + (size_t)gid * 4);
  int gx = (int)nc.y, gy = (int)nc.z, gz = (int)nc.w;
  int xs = min(max(gx, 0), LM - 1);
  int ys = min(max(gy, 0), LM - 1);
  out_maps[((size_t)(b*4 + 1) * LM + xs) * LM + ys] = 1.0f;
  if (gz >= 13 && gz <= 25)
    out_maps[((size_t)(b*4 + 0) * LM + xs) * LM + ys] = 1.0f;
}

extern "C" void kernel_launch(void* const* d_in, const int* in_sizes, int n_in,
                              void* d_out, int out_size, void* d_ws, size_t ws_size,
                              hipStream_t stream) {
  const float* obs        = (const float*)d_in[0];
  const float* pose_obs   = (const float*)d_in[1];
  const float* poses_last = (const float*)d_in[4];
  const float* map_last   = (const float*)d_in[5];
  float* out = (float*)d_out;

  const size_t FIRST_BYTES = (size_t)BSZ * NVOXB * sizeof(int);  // 25.6 MB
  bool use_ws = ws_size >= FIRST_BYTES + 4096;
  float* params = (float*)d_ws;   // 128 B
  int*   first  = use_ws ? (int*)((char*)d_ws + 4096) : (int*)(out + OFF_MAPS);

  float focf = (float)((double)WW / 2.0 / tan(39.5 * (M_PI / 180.0)));
  float rfoc = (float)(1.0 / (double)focf);

  hipLaunchKernelGGL(pose_kernel, dim3(1), dim3(64), 0, stream,
                     pose_obs, poses_last, out + OFF_POSES, params);
  hipLaunchKernelGGL(vox_store, dim3((VOXWORK + 255) / 256), dim3(256), 0, stream,
                     obs, first, rfoc);
  if (use_ws) {
    // refine + map-copy in one launch; fused writes maps directly afterwards
    hipLaunchKernelGGL(vox_refine_copy, dim3((VOXWORK + NC + 255) / 256), dim3(256), 0, stream,
                       obs, first, rfoc, map_last, out + OFF_MAPS, 1);
    hipLaunchKernelGGL(fused_kernel, dim3((BSZ * NPIX + 255) / 256), dim3(256), 0, stream,
                       obs, first, params, out, rfoc, 1);
  } else {
    // round-10 proven path: first[] aliases maps region; scatter deferred
    hipLaunchKernelGGL(vox_refine_copy, dim3((VOXWORK + 255) / 256), dim3(256), 0, stream,
                       obs, first, rfoc, map_last, out + OFF_MAPS, 0);
    hipLaunchKernelGGL(fused_kernel, dim3((BSZ * NPIX + 255) / 256), dim3(256), 0, stream,
                       obs, first, params, out, rfoc, 0);
    hipLaunchKernelGGL(copy_maps, dim3((NC + 255) / 256), dim3(256), 0, stream,
                       map_last, out + OFF_MAPS);
    hipLaunchKernelGGL(scatter_maps, dim3((BSZ * NPIX + 255) / 256), dim3(256), 0, stream,
                       out + OFF_COORDS, out + OFF_REP, out + OFF_MAPS);
  }
}

// Round 12
// 122.030 us; speedup vs baseline: 1.4701x; 1.0884x over previous
//
#include <hip/hip_runtime.h>
#include <math.h>

#define BSZ 8
#define HH 480
#define WW 640
#define NPIX (HH*WW)          // 307200
#define VRES 100
#define NZB 80
#define NVOXB (VRES*VRES*NZB) // 800000
#define LM 480

// output layout (flat float32, return order)
#define OFF_COORDS 0LL
#define OFF_FEAT   9830400LL                     // 8*307200*4
#define OFF_MAPS   29491200LL                    // + 8*307200*8
#define OFF_POSES  36864000LL                    // + 8*4*480*480
#define OFF_REP    36864024LL                    // + 24

typedef float fx4 __attribute__((ext_vector_type(4)));

struct PtRes { float depth, X, Z; int g0, g1, g2, vox; bool valid; };

// locality voxel id: (c2, c0) near-constant per wave, c1 minor dim
__device__ __forceinline__ int voxid(int c0, int c1, int c2) {
  return (c2 * VRES + c0) * VRES + c1;
}

// PASSING arithmetic chain (round 6) — do not perturb:
// fast-math reciprocal multiplies: /100 -> *0.01f, /FOC -> *f32(1/FOC), /0.05 -> *20.0f
__device__ __forceinline__ PtRes compute_pt(float draw, int u, int r, float rfoc) {
  PtRes p;
  p.depth = __fmul_rn(draw, 0.01f);
  p.X = __fadd_rn(__fmul_rn(__fmul_rn(__fsub_rn((float)u, 319.5f), p.depth), rfoc), 2.5f);
  p.Z = __fadd_rn(__fmul_rn(__fmul_rn(__fsub_rn((float)(HH - 1 - r), 239.5f), p.depth), rfoc), 0.88f);
  p.valid = (p.X > 0.0f) & (p.X < 5.0f) & (p.depth > 0.0f) & (p.depth < 5.0f)
          & (p.Z > -0.4f) & (p.Z < 3.6f);
  p.g0 = (int)floorf(__fmul_rn(p.X, 20.0f));
  p.g1 = (int)floorf(__fmul_rn(p.depth, 20.0f));
  p.g2 = (int)floorf(__fmul_rn(p.Z, 20.0f));
  int c0 = min(max(p.g0, 0), VRES - 1);
  int c1 = min(max(p.g1, 0), VRES - 1);
  int c2 = min(max(p.g2 + 8, 0), NZB - 1);
  p.vox = voxid(c0, c1, c2);
  return p;
}

__global__ void pose_kernel(const float* __restrict__ pose_obs,
                            const float* __restrict__ poses_last,
                            float* __restrict__ out_poses,
                            float* __restrict__ params) {
  int b = threadIdx.x;
  if (b >= BSZ) return;
  float p0 = poses_last[b*3+0], p1 = poses_last[b*3+1], p2 = poses_last[b*3+2];
  float r0 = pose_obs[b*3+0],  r1 = pose_obs[b*3+1],  r2 = pose_obs[b*3+2];
  const float DEGf = (float)57.29577951308232;
  float thf = __fmul_rn(p2, (float)0.017453292519943295);
  float sth = (float)sin((double)thf);
  float cth = (float)cos((double)thf);
  float y = __fadd_rn(__fadd_rn(p1, __fmul_rn(r0, sth)), __fmul_rn(r1, cth));
  float x = __fsub_rn(__fadd_rn(p0, __fmul_rn(r0, cth)), __fmul_rn(r1, sth));
  float t = __fadd_rn(p2, __fmul_rn(r2, DEGf));
  t = __fadd_rn(fmodf(__fsub_rn(t, 180.0f), 360.0f), 180.0f);
  t = __fsub_rn(fmodf(__fadd_rn(t, 180.0f), 360.0f), 180.0f);
  out_poses[b*3+0] = x; out_poses[b*3+1] = y; out_poses[b*3+2] = t;
  float st0 = __fmul_rn(__fmul_rn(x, 100.0f), 0.2f);
  float st1 = __fmul_rn(__fmul_rn(y, 100.0f), 0.2f);
  float st2 = __fsub_rn(90.0f, t);
  float trad = __fmul_rn(st2, (float)(M_PI / 180.0));
  params[b*4+0] = (float)cos((double)trad);   // c
  params[b*4+1] = (float)sin((double)trad);   // s
  params[b*4+2] = st1;                        // trans[0]
  params[b*4+3] = st0;                        // trans[1]
}

#define VPT 8
#define TPB_ROWS (NPIX / VPT)          // 38400 threads per batch
#define VOXBLK (BSZ * TPB_ROWS / 256)  // 1200 blocks
#define NC (BSZ * 4 * LM * LM / 4)     // 1,843,200 float4 copies
#define NCBLK (NC / 256)               // 7200 blocks

// phase 1: racy plain stores — XCD-pinned: batch = blockIdx % 8 so each batch's
// 3.2 MB first[] slice stays in ONE XCD's L2 (round-robin dispatch).
__global__ __launch_bounds__(256) void vox_store(const float* __restrict__ obs,
                                                 int* __restrict__ first, float rfoc) {
  int b   = blockIdx.x & 7;
  int t   = (blockIdx.x >> 3) * 256 + threadIdx.x;   // 0..38399
  int n0 = t * VPT;
  int r = n0 / WW, u0 = n0 % WW;
  const float* rowp = obs + ((size_t)(b*4 + 3) * HH + r) * WW + u0;
  float4 da = *(const float4*)(rowp);
  float4 db = *(const float4*)(rowp + 4);
  float dv[VPT] = {da.x, da.y, da.z, da.w, db.x, db.y, db.z, db.w};
  int* fb = first + b * NVOXB;
  #pragma unroll
  for (int k = 0; k < VPT; ++k) {
    PtRes p = compute_pt(dv[k], u0 + k, r, rfoc);
    if (p.valid) fb[p.vox] = n0 + k;
  }
}

// phase 2 (+ map copy in the same launch): XCD-pinned refine; only pixels
// beating the stored candidate issue a device atomic.
__global__ __launch_bounds__(256) void vox_refine_copy(const float* __restrict__ obs,
                                                       int* __restrict__ first, float rfoc,
                                                       const float* __restrict__ map_last,
                                                       float* __restrict__ out_maps,
                                                       int do_copy) {
  int bid = blockIdx.x;
  if (bid < VOXBLK) {
    int b = bid & 7;
    int t = (bid >> 3) * 256 + threadIdx.x;
    int n0 = t * VPT;
    int r = n0 / WW, u0 = n0 % WW;
    const float* rowp = obs + ((size_t)(b*4 + 3) * HH + r) * WW + u0;
    float4 da = *(const float4*)(rowp);
    float4 db = *(const float4*)(rowp + 4);
    float dv[VPT] = {da.x, da.y, da.z, da.w, db.x, db.y, db.z, db.w};
    int* fb = first + b * NVOXB;
    #pragma unroll
    for (int k = 0; k < VPT; ++k) {
      PtRes p = compute_pt(dv[k], u0 + k, r, rfoc);
      if (p.valid) {
        int n = n0 + k;
        if (n < fb[p.vox]) atomicMin(&fb[p.vox], n);
      }
    }
  } else if (do_copy) {
    int j = (bid - VOXBLK) * 256 + threadIdx.x;
    if (j < NC)
      *(float4*)(out_maps + (size_t)j * 4) = *(const float4*)(map_last + (size_t)j * 4);
  }
}

// fused: coords + rep + feats (+ maps scatter on ws path), XCD-pinned per batch
__global__ __launch_bounds__(256) void fused_kernel(const float* __restrict__ obs,
                                                    const int* __restrict__ first,
                                                    const float* __restrict__ params,
                                                    float* __restrict__ out, float rfoc,
                                                    int write_maps) {
  int b = blockIdx.x & 7;
  int n = (blockIdx.x >> 3) * 256 + threadIdx.x;     // 0..NPIX-1
  int gid = b * NPIX + n;
  int r = n / WW, u = n % WW;
  float draw = obs[((size_t)(b*4 + 3) * HH + r) * WW + u];
  PtRes p = compute_pt(draw, u, r, rfoc);
  bool rep = p.valid && (first[b * NVOXB + p.vox] == n);

  float c   = params[b*4+0], s = params[b*4+1];
  float tr0 = params[b*4+2], tr1 = params[b*4+3];

  float gcf0 = (float)p.g1, gcf1 = (float)(p.g0 - 50);
  float d0 = fmaf(gcf1, -s, __fmul_rn(gcf0, c));
  float d1 = fmaf(gcf1,  c, __fmul_rn(gcf0, s));
  int gx = (int)rintf(__fadd_rn(d0, tr0));
  int gy = (int)rintf(__fadd_rn(d1, tr1));
  int gz = p.g2 + 8;

  fx4 ncv = rep ? (fx4){(float)b, (float)gx, (float)gy, (float)gz}
                : (fx4){0.f, 0.f, 0.f, 0.f};
  __builtin_nontemporal_store(ncv, (fx4*)(out + OFF_COORDS + (size_t)gid * 4));
  out[OFF_REP + gid] = rep ? 1.0f : 0.0f;

  fx4 f0 = {0.f, 0.f, 0.f, 0.f};
  fx4 f1 = {0.f, 0.f, 0.f, 0.f};
  if (rep) {
    float cf0 = p.depth;
    float cf1 = __fsub_rn(p.X, 2.5f);
    float e0 = __fadd_rn(fmaf(cf1, -s, __fmul_rn(cf0, c)), __fmul_rn(tr0, 0.05f));
    float e1 = __fadd_rn(fmaf(cf1,  c, __fmul_rn(cf0, s)), __fmul_rn(tr1, 0.05f));
    float e2 = __fadd_rn(p.Z, 0.4f);
    float R  = obs[((size_t)(b*4 + 0) * HH + r) * WW + u];
    float G  = obs[((size_t)(b*4 + 1) * HH + r) * WW + u];
    float Bv = obs[((size_t)(b*4 + 2) * HH + r) * WW + u];
    f0 = (fx4){e0, e1, e2, R};
    f1 = (fx4){G, Bv, 0.f, 0.f};
  }
  __builtin_nontemporal_store(f0, (fx4*)(out + OFF_FEAT + (size_t)gid * 8));
  __builtin_nontemporal_store(f1, (fx4*)(out + OFF_FEAT + (size_t)gid * 8 + 4));

  if (write_maps && rep) {
    int xs = min(max(gx, 0), LM - 1);
    int ys = min(max(gy, 0), LM - 1);
    out[OFF_MAPS + ((size_t)(b*4 + 1) * LM + xs) * LM + ys] = 1.0f;
    if (gz >= 13 && gz <= 25)
      out[OFF_MAPS + ((size_t)(b*4 + 0) * LM + xs) * LM + ys] = 1.0f;
  }
}

__global__ __launch_bounds__(256) void copy_maps(const float* __restrict__ map_last,
                                                 float* __restrict__ out_maps) {
  int i = blockIdx.x * blockDim.x + threadIdx.x;
  if (i < NC)
    *(float4*)(out_maps + (size_t)i * 4) = *(const float4*)(map_last + (size_t)i * 4);
}

// fallback-only: scatter from already-written coords+rep
__global__ __launch_bounds__(256) void scatter_maps(const float* __restrict__ out_coords,
                                                    const float* __restrict__ rep_flags,
                                                    float* __restrict__ out_maps) {
  int gid = blockIdx.x * blockDim.x + threadIdx.x;
  if (gid >= BSZ * NPIX) return;
  if (rep_flags[gid] == 0.0f) return;
  int b = gid / NPIX;
  float4 nc = *(const float4*)(out_coords + (size_t)gid * 4);
  int gx = (int)nc.y, gy = (int)nc.z, gz = (int)nc.w;
  int xs = min(max(gx, 0), LM - 1);
  int ys = min(max(gy, 0), LM - 1);
  out_maps[((size_t)(b*4 + 1) * LM + xs) * LM + ys] = 1.0f;
  if (gz >= 13 && gz <= 25)
    out_maps[((size_t)(b*4 + 0) * LM + xs) * LM + ys] = 1.0f;
}

extern "C" void kernel_launch(void* const* d_in, const int* in_sizes, int n_in,
                              void* d_out, int out_size, void* d_ws, size_t ws_size,
                              hipStream_t stream) {
  const float* obs        = (const float*)d_in[0];
  const float* pose_obs   = (const float*)d_in[1];
  const float* poses_last = (const float*)d_in[4];
  const float* map_last   = (const float*)d_in[5];
  float* out = (float*)d_out;

  const size_t FIRST_BYTES = (size_t)BSZ * NVOXB * sizeof(int);  // 25.6 MB
  bool use_ws = ws_size >= FIRST_BYTES + 4096;
  float* params = (float*)d_ws;   // 128 B
  int*   first  = use_ws ? (int*)((char*)d_ws + 4096) : (int*)(out + OFF_MAPS);

  float focf = (float)((double)WW / 2.0 / tan(39.5 * (M_PI / 180.0)));
  float rfoc = (float)(1.0 / (double)focf);

  hipLaunchKernelGGL(pose_kernel, dim3(1), dim3(64), 0, stream,
                     pose_obs, poses_last, out + OFF_POSES, params);
  hipLaunchKernelGGL(vox_store, dim3(VOXBLK), dim3(256), 0, stream, obs, first, rfoc);
  if (use_ws) {
    hipLaunchKernelGGL(vox_refine_copy, dim3(VOXBLK + NCBLK), dim3(256), 0, stream,
                       obs, first, rfoc, map_last, out + OFF_MAPS, 1);
    hipLaunchKernelGGL(fused_kernel, dim3(BSZ * NPIX / 256), dim3(256), 0, stream,
                       obs, first, params, out, rfoc, 1);
  } else {
    hipLaunchKernelGGL(vox_refine_copy, dim3(VOXBLK), dim3(256), 0, stream,
                       obs, first, rfoc, map_last, out + OFF_MAPS, 0);
    hipLaunchKernelGGL(fused_kernel, dim3(BSZ * NPIX / 256), dim3(256), 0, stream,
                       obs, first, params, out, rfoc, 0);
    hipLaunchKernelGGL(copy_maps, dim3((NC + 255) / 256), dim3(256), 0, stream,
                       map_last, out + OFF_MAPS);
    hipLaunchKernelGGL(scatter_maps, dim3((BSZ * NPIX + 255) / 256), dim3(256), 0, stream,
                       out + OFF_COORDS, out + OFF_REP, out + OFF_MAPS);
  }
}

// Round 13
// 121.787 us; speedup vs baseline: 1.4730x; 1.0020x over previous
//
#include <hip/hip_runtime.h>
#include <hip/hip_cooperative_groups.h>
#include <math.h>

namespace cg = cooperative_groups;

#define BSZ 8
#define HH 480
#define WW 640
#define NPIX (HH*WW)          // 307200
#define VRES 100
#define NZB 80
#define NVOXB (VRES*VRES*NZB) // 800000
#define LM 480

// output layout (flat float32, return order)
#define OFF_COORDS 0LL
#define OFF_FEAT   9830400LL
#define OFF_MAPS   29491200LL
#define OFF_POSES  36864000LL
#define OFF_REP    36864024LL

typedef float fx4 __attribute__((ext_vector_type(4)));

struct PtRes { float depth, X, Z; int g0, g1, g2, vox; bool valid; };

__device__ __forceinline__ int voxid(int c0, int c1, int c2) {
  return (c2 * VRES + c0) * VRES + c1;   // (c2,c0) near-constant per wave
}

// PASSING arithmetic chain (round 6) — do not perturb.
__device__ __forceinline__ PtRes compute_pt(float draw, int u, int r, float rfoc) {
  PtRes p;
  p.depth = __fmul_rn(draw, 0.01f);
  p.X = __fadd_rn(__fmul_rn(__fmul_rn(__fsub_rn((float)u, 319.5f), p.depth), rfoc), 2.5f);
  p.Z = __fadd_rn(__fmul_rn(__fmul_rn(__fsub_rn((float)(HH - 1 - r), 239.5f), p.depth), rfoc), 0.88f);
  p.valid = (p.X > 0.0f) & (p.X < 5.0f) & (p.depth > 0.0f) & (p.depth < 5.0f)
          & (p.Z > -0.4f) & (p.Z < 3.6f);
  p.g0 = (int)floorf(__fmul_rn(p.X, 20.0f));
  p.g1 = (int)floorf(__fmul_rn(p.depth, 20.0f));
  p.g2 = (int)floorf(__fmul_rn(p.Z, 20.0f));
  int c0 = min(max(p.g0, 0), VRES - 1);
  int c1 = min(max(p.g1, 0), VRES - 1);
  int c2 = min(max(p.g2 + 8, 0), NZB - 1);
  p.vox = voxid(c0, c1, c2);
  return p;
}

__device__ __forceinline__ void pose_calc(int b, const float* pose_obs,
                                          const float* poses_last,
                                          float* out_poses, float* params) {
  float p0 = poses_last[b*3+0], p1 = poses_last[b*3+1], p2 = poses_last[b*3+2];
  float r0 = pose_obs[b*3+0],  r1 = pose_obs[b*3+1],  r2 = pose_obs[b*3+2];
  const float DEGf = (float)57.29577951308232;
  float thf = __fmul_rn(p2, (float)0.017453292519943295);
  float sth = (float)sin((double)thf);
  float cth = (float)cos((double)thf);
  float y = __fadd_rn(__fadd_rn(p1, __fmul_rn(r0, sth)), __fmul_rn(r1, cth));
  float x = __fsub_rn(__fadd_rn(p0, __fmul_rn(r0, cth)), __fmul_rn(r1, sth));
  float t = __fadd_rn(p2, __fmul_rn(r2, DEGf));
  t = __fadd_rn(fmodf(__fsub_rn(t, 180.0f), 360.0f), 180.0f);
  t = __fsub_rn(fmodf(__fadd_rn(t, 180.0f), 360.0f), 180.0f);
  out_poses[b*3+0] = x; out_poses[b*3+1] = y; out_poses[b*3+2] = t;
  float st0 = __fmul_rn(__fmul_rn(x, 100.0f), 0.2f);
  float st1 = __fmul_rn(__fmul_rn(y, 100.0f), 0.2f);
  float st2 = __fsub_rn(90.0f, t);
  float trad = __fmul_rn(st2, (float)(M_PI / 180.0));
  params[b*4+0] = (float)cos((double)trad);
  params[b*4+1] = (float)sin((double)trad);
  params[b*4+2] = st1;
  params[b*4+3] = st0;
}

#define VPT 8
#define TPB_ROWS (NPIX / VPT)          // 38400 threads per batch
#define VOXBLK (BSZ * TPB_ROWS / 256)  // 1200 blocks
#define NC (BSZ * 4 * LM * LM / 4)     // 1,843,200 float4 copies
#define NCB (NC / 8)                   // per-batch float4 copies (230400)
#define NCBLK (NC / 256)

// ---------------- cooperative single-kernel path ----------------
__global__ __launch_bounds__(256, 5) void coop_all(const float* __restrict__ obs,
                                                   int* __restrict__ first,
                                                   float* __restrict__ params,
                                                   float* __restrict__ out, float rfoc,
                                                   const float* __restrict__ pose_obs,
                                                   const float* __restrict__ poses_last,
                                                   const float* __restrict__ map_last) {
  cg::grid_group grid = cg::this_grid();
  int b = blockIdx.x & 7;                         // XCD-pin per batch
  int t = (blockIdx.x >> 3) * 256 + threadIdx.x;  // 0..38399
  int n0 = t * VPT;
  int r = n0 / WW, u0 = n0 % WW;

  if (blockIdx.x == 0 && threadIdx.x < BSZ)
    pose_calc(threadIdx.x, pose_obs, poses_last, out + OFF_POSES, params);

  // ---- phase 1: depth load, racy candidate stores, XCD-pinned map copy ----
  const float* rowp = obs + ((size_t)(b*4 + 3) * HH + r) * WW + u0;
  float4 da = *(const float4*)(rowp);
  float4 db = *(const float4*)(rowp + 4);
  float dv[VPT] = {da.x, da.y, da.z, da.w, db.x, db.y, db.z, db.w};
  int vox[VPT]; unsigned vmask = 0;
  int* fb = first + b * NVOXB;
  #pragma unroll
  for (int k = 0; k < VPT; ++k) {
    PtRes p = compute_pt(dv[k], u0 + k, r, rfoc);
    vox[k] = p.vox;
    if (p.valid) { vmask |= (1u << k); fb[p.vox] = n0 + k; }
  }
  {
    float* om = out + OFF_MAPS;
    #pragma unroll
    for (int it = 0; it < 6; ++it) {              // 6*38400 == NCB exactly
      int j = b * NCB + t + it * TPB_ROWS;
      *(float4*)(om + (size_t)j * 4) = *(const float4*)(map_last + (size_t)j * 4);
    }
  }
  __threadfence();
  grid.sync();

  // ---- phase 2: refine (atomic only when beating the stored candidate) ----
  #pragma unroll
  for (int k = 0; k < VPT; ++k) {
    if (vmask & (1u << k)) {
      int n = n0 + k;
      if (n < fb[vox[k]]) atomicMin(&fb[vox[k]], n);
    }
  }
  __threadfence();
  grid.sync();

  // ---- phase 3: rep + coords + feats + maps scatter ----
  float c   = params[b*4+0], s = params[b*4+1];
  float tr0 = params[b*4+2], tr1 = params[b*4+3];
  size_t gid0 = (size_t)b * NPIX + n0;

  fx4 repv[2] = {{0.f,0.f,0.f,0.f},{0.f,0.f,0.f,0.f}};
  #pragma unroll
  for (int g = 0; g < 2; ++g) {
    const float* Rp = obs + ((size_t)(b*4 + 0) * HH + r) * WW + u0 + g*4;
    const float* Gp = obs + ((size_t)(b*4 + 1) * HH + r) * WW + u0 + g*4;
    const float* Bp = obs + ((size_t)(b*4 + 2) * HH + r) * WW + u0 + g*4;
    float4 R4 = *(const float4*)(Rp);
    float4 G4 = *(const float4*)(Gp);
    float4 B4 = *(const float4*)(Bp);
    float Rv[4] = {R4.x, R4.y, R4.z, R4.w};
    float Gv[4] = {G4.x, G4.y, G4.z, G4.w};
    float Bv4[4] = {B4.x, B4.y, B4.z, B4.w};
    #pragma unroll
    for (int q = 0; q < 4; ++q) {
      int k = g*4 + q;
      int n = n0 + k;
      PtRes p = compute_pt(dv[k], u0 + k, r, rfoc);
      bool rep = ((vmask >> k) & 1u) && (fb[vox[k]] == n);

      float gcf0 = (float)p.g1, gcf1 = (float)(p.g0 - 50);
      float d0 = fmaf(gcf1, -s, __fmul_rn(gcf0, c));
      float d1 = fmaf(gcf1,  c, __fmul_rn(gcf0, s));
      int gx = (int)rintf(__fadd_rn(d0, tr0));
      int gy = (int)rintf(__fadd_rn(d1, tr1));
      int gz = p.g2 + 8;

      fx4 ncv = rep ? (fx4){(float)b, (float)gx, (float)gy, (float)gz}
                    : (fx4){0.f, 0.f, 0.f, 0.f};
      __builtin_nontemporal_store(ncv, (fx4*)(out + OFF_COORDS + (gid0 + k) * 4));

      fx4 f0 = {0.f,0.f,0.f,0.f}, f1 = {0.f,0.f,0.f,0.f};
      if (rep) {
        float cf0 = p.depth;
        float cf1 = __fsub_rn(p.X, 2.5f);
        float e0 = __fadd_rn(fmaf(cf1, -s, __fmul_rn(cf0, c)), __fmul_rn(tr0, 0.05f));
        float e1 = __fadd_rn(fmaf(cf1,  c, __fmul_rn(cf0, s)), __fmul_rn(tr1, 0.05f));
        float e2 = __fadd_rn(p.Z, 0.4f);
        f0 = (fx4){e0, e1, e2, Rv[q]};
        f1 = (fx4){Gv[q], Bv4[q], 0.f, 0.f};
        repv[g][q] = 1.0f;

        int xs = min(max(gx, 0), LM - 1);
        int ys = min(max(gy, 0), LM - 1);
        out[OFF_MAPS + ((size_t)(b*4 + 1) * LM + xs) * LM + ys] = 1.0f;
        if (gz >= 13 && gz <= 25)
          out[OFF_MAPS + ((size_t)(b*4 + 0) * LM + xs) * LM + ys] = 1.0f;
      }
      __builtin_nontemporal_store(f0, (fx4*)(out + OFF_FEAT + (gid0 + k) * 8));
      __builtin_nontemporal_store(f1, (fx4*)(out + OFF_FEAT + (gid0 + k) * 8 + 4));
    }
  }
  __builtin_nontemporal_store(repv[0], (fx4*)(out + OFF_REP + gid0));
  __builtin_nontemporal_store(repv[1], (fx4*)(out + OFF_REP + gid0 + 4));
}

// ---------------- fallback multi-kernel path (round 12, proven) ----------------
__global__ void pose_kernel(const float* __restrict__ pose_obs,
                            const float* __restrict__ poses_last,
                            float* __restrict__ out_poses,
                            float* __restrict__ params) {
  int b = threadIdx.x;
  if (b < BSZ) pose_calc(b, pose_obs, poses_last, out_poses, params);
}

__global__ __launch_bounds__(256) void vox_store(const float* __restrict__ obs,
                                                 int* __restrict__ first, float rfoc) {
  int b   = blockIdx.x & 7;
  int t   = (blockIdx.x >> 3) * 256 + threadIdx.x;
  int n0 = t * VPT;
  int r = n0 / WW, u0 = n0 % WW;
  const float* rowp = obs + ((size_t)(b*4 + 3) * HH + r) * WW + u0;
  float4 da = *(const float4*)(rowp);
  float4 db = *(const float4*)(rowp + 4);
  float dv[VPT] = {da.x, da.y, da.z, da.w, db.x, db.y, db.z, db.w};
  int* fb = first + b * NVOXB;
  #pragma unroll
  for (int k = 0; k < VPT; ++k) {
    PtRes p = compute_pt(dv[k], u0 + k, r, rfoc);
    if (p.valid) fb[p.vox] = n0 + k;
  }
}

__global__ __launch_bounds__(256) void vox_refine_copy(const float* __restrict__ obs,
                                                       int* __restrict__ first, float rfoc,
                                                       const float* __restrict__ map_last,
                                                       float* __restrict__ out_maps,
                                                       int do_copy) {
  int bid = blockIdx.x;
  if (bid < VOXBLK) {
    int b = bid & 7;
    int t = (bid >> 3) * 256 + threadIdx.x;
    int n0 = t * VPT;
    int r = n0 / WW, u0 = n0 % WW;
    const float* rowp = obs + ((size_t)(b*4 + 3) * HH + r) * WW + u0;
    float4 da = *(const float4*)(rowp);
    float4 db = *(const float4*)(rowp + 4);
    float dv[VPT] = {da.x, da.y, da.z, da.w, db.x, db.y, db.z, db.w};
    int* fb = first + b * NVOXB;
    #pragma unroll
    for (int k = 0; k < VPT; ++k) {
      PtRes p = compute_pt(dv[k], u0 + k, r, rfoc);
      if (p.valid) {
        int n = n0 + k;
        if (n < fb[p.vox]) atomicMin(&fb[p.vox], n);
      }
    }
  } else if (do_copy) {
    int j = (bid - VOXBLK) * 256 + threadIdx.x;
    if (j < NC)
      *(float4*)(out_maps + (size_t)j * 4) = *(const float4*)(map_last + (size_t)j * 4);
  }
}

__global__ __launch_bounds__(256) void fused_kernel(const float* __restrict__ obs,
                                                    const int* __restrict__ first,
                                                    const float* __restrict__ params,
                                                    float* __restrict__ out, float rfoc,
                                                    int write_maps) {
  int b = blockIdx.x & 7;
  int n = (blockIdx.x >> 3) * 256 + threadIdx.x;
  int gid = b * NPIX + n;
  int r = n / WW, u = n % WW;
  float draw = obs[((size_t)(b*4 + 3) * HH + r) * WW + u];
  PtRes p = compute_pt(draw, u, r, rfoc);
  bool rep = p.valid && (first[b * NVOXB + p.vox] == n);

  float c   = params[b*4+0], s = params[b*4+1];
  float tr0 = params[b*4+2], tr1 = params[b*4+3];

  float gcf0 = (float)p.g1, gcf1 = (float)(p.g0 - 50);
  float d0 = fmaf(gcf1, -s, __fmul_rn(gcf0, c));
  float d1 = fmaf(gcf1,  c, __fmul_rn(gcf0, s));
  int gx = (int)rintf(__fadd_rn(d0, tr0));
  int gy = (int)rintf(__fadd_rn(d1, tr1));
  int gz = p.g2 + 8;

  fx4 ncv = rep ? (fx4){(float)b, (float)gx, (float)gy, (float)gz}
                : (fx4){0.f, 0.f, 0.f, 0.f};
  __builtin_nontemporal_store(ncv, (fx4*)(out + OFF_COORDS + (size_t)gid * 4));
  out[OFF_REP + gid] = rep ? 1.0f : 0.0f;

  fx4 f0 = {0.f, 0.f, 0.f, 0.f};
  fx4 f1 = {0.f, 0.f, 0.f, 0.f};
  if (rep) {
    float cf0 = p.depth;
    float cf1 = __fsub_rn(p.X, 2.5f);
    float e0 = __fadd_rn(fmaf(cf1, -s, __fmul_rn(cf0, c)), __fmul_rn(tr0, 0.05f));
    float e1 = __fadd_rn(fmaf(cf1,  c, __fmul_rn(cf0, s)), __fmul_rn(tr1, 0.05f));
    float e2 = __fadd_rn(p.Z, 0.4f);
    float R  = obs[((size_t)(b*4 + 0) * HH + r) * WW + u];
    float G  = obs[((size_t)(b*4 + 1) * HH + r) * WW + u];
    float Bv = obs[((size_t)(b*4 + 2) * HH + r) * WW + u];
    f0 = (fx4){e0, e1, e2, R};
    f1 = (fx4){G, Bv, 0.f, 0.f};
  }
  __builtin_nontemporal_store(f0, (fx4*)(out + OFF_FEAT + (size_t)gid * 8));
  __builtin_nontemporal_store(f1, (fx4*)(out + OFF_FEAT + (size_t)gid * 8 + 4));

  if (write_maps && rep) {
    int xs = min(max(gx, 0), LM - 1);
    int ys = min(max(gy, 0), LM - 1);
    out[OFF_MAPS + ((size_t)(b*4 + 1) * LM + xs) * LM + ys] = 1.0f;
    if (gz >= 13 && gz <= 25)
      out[OFF_MAPS + ((size_t)(b*4 + 0) * LM + xs) * LM + ys] = 1.0f;
  }
}

__global__ __launch_bounds__(256) void copy_maps(const float* __restrict__ map_last,
                                                 float* __restrict__ out_maps) {
  int i = blockIdx.x * blockDim.x + threadIdx.x;
  if (i < NC)
    *(float4*)(out_maps + (size_t)i * 4) = *(const float4*)(map_last + (size_t)i * 4);
}

__global__ __launch_bounds__(256) void scatter_maps(const float* __restrict__ out_coords,
                                                    const float* __restrict__ rep_flags,
                                                    float* __restrict__ out_maps) {
  int gid = blockIdx.x * blockDim.x + threadIdx.x;
  if (gid >= BSZ * NPIX) return;
  if (rep_flags[gid] == 0.0f) return;
  int b = gid / NPIX;
  float4 nc = *(const float4*)(out_coords + (size_t)gid * 4);
  int gx = (int)nc.y, gy = (int)nc.z, gz = (int)nc.w;
  int xs = min(max(gx, 0), LM - 1);
  int ys = min(max(gy, 0), LM - 1);
  out_maps[((size_t)(b*4 + 1) * LM + xs) * LM + ys] = 1.0f;
  if (gz >= 13 && gz <= 25)
    out_maps[((size_t)(b*4 + 0) * LM + xs) * LM + ys] = 1.0f;
}

extern "C" void kernel_launch(void* const* d_in, const int* in_sizes, int n_in,
                              void* d_out, int out_size, void* d_ws, size_t ws_size,
                              hipStream_t stream) {
  const float* obs        = (const float*)d_in[0];
  const float* pose_obs   = (const float*)d_in[1];
  const float* poses_last = (const float*)d_in[4];
  const float* map_last   = (const float*)d_in[5];
  float* out = (float*)d_out;

  const size_t FIRST_BYTES = (size_t)BSZ * NVOXB * sizeof(int);  // 25.6 MB
  bool use_ws = ws_size >= FIRST_BYTES + 4096;
  float* params = (float*)d_ws;
  int*   first  = use_ws ? (int*)((char*)d_ws + 4096) : (int*)(out + OFF_MAPS);

  float focf = (float)((double)WW / 2.0 / tan(39.5 * (M_PI / 180.0)));
  float rfoc = (float)(1.0 / (double)focf);

  bool coop_ok = false;
  if (use_ws) {
    int maxB = 0;
    if (hipOccupancyMaxActiveBlocksPerMultiprocessor(&maxB, coop_all, 256, 0) == hipSuccess)
      coop_ok = (maxB >= 5);   // 5 blocks/CU x 256 CUs = 1280 >= 1200 co-resident
  }

  if (coop_ok) {
    void* args[] = {(void*)&obs, (void*)&first, (void*)&params, (void*)&out,
                    (void*)&rfoc, (void*)&pose_obs, (void*)&poses_last, (void*)&map_last};
    hipLaunchCooperativeKernel((const void*)coop_all, dim3(VOXBLK), dim3(256),
                               args, 0, stream);
  } else if (use_ws) {
    hipLaunchKernelGGL(pose_kernel, dim3(1), dim3(64), 0, stream,
                       pose_obs, poses_last, out + OFF_POSES, params);
    hipLaunchKernelGGL(vox_store, dim3(VOXBLK), dim3(256), 0, stream, obs, first, rfoc);
    hipLaunchKernelGGL(vox_refine_copy, dim3(VOXBLK + NCBLK), dim3(256), 0, stream,
                       obs, first, rfoc, map_last, out + OFF_MAPS, 1);
    hipLaunchKernelGGL(fused_kernel, dim3(BSZ * NPIX / 256), dim3(256), 0, stream,
                       obs, first, params, out, rfoc, 1);
  } else {
    hipLaunchKernelGGL(pose_kernel, dim3(1), dim3(64), 0, stream,
                       pose_obs, poses_last, out + OFF_POSES, params);
    hipLaunchKernelGGL(vox_store, dim3(VOXBLK), dim3(256), 0, stream, obs, first, rfoc);
    hipLaunchKernelGGL(vox_refine_copy, dim3(VOXBLK), dim3(256), 0, stream,
                       obs, first, rfoc, map_last, out + OFF_MAPS, 0);
    hipLaunchKernelGGL(fused_kernel, dim3(BSZ * NPIX / 256), dim3(256), 0, stream,
                       obs, first, params, out, rfoc, 0);
    hipLaunchKernelGGL(copy_maps, dim3((NC + 255) / 256), dim3(256), 0, stream,
                       map_last, out + OFF_MAPS);
    hipLaunchKernelGGL(scatter_maps, dim3((BSZ * NPIX + 255) / 256), dim3(256), 0, stream,
                       out + OFF_COORDS, out + OFF_REP, out + OFF_MAPS);
  }
}